// Round 7
// baseline (327.077 us; speedup 1.0000x reference)
//
#include <hip/hip_runtime.h>
#include <hip/hip_bf16.h>
#include <math.h>

#define BB 4096
#define DD 256
#define GG 100
#define GAMMA_C 0.8f
#define RHO_C 8.0f
#define ALPHA_C 0.5f
#define EPS_C 1e-14f
#define NS2 64   // 64 stripes (2 per 128-tile: one per 64-wide wave)

typedef __bf16 bf16x8 __attribute__((ext_vector_type(8)));
typedef float f32x4 __attribute__((ext_vector_type(4)));

// MFMA-fragment-swizzled layout: element (r,k) ->
//   row_blk=r>>4 (stride 4096 = 16 rows x 256 k), step=k>>5 (stride 512 =
//   16 rows x 32 k), kq2=(k>>3)&3 (stride 128), ml=r&15 (stride 8), pos=k&7.
// Fields pack exactly: 3+4+2+3 = 12 bits per row_blk -> NO holes, total
// span = 256*4096 = BB*DD.  [R6 bug: strides 8192/1024 left a hole at bit 9
// and overran the allocation by 2x -> cross-array clobber -> NaN]
__device__ inline int swz(int r, int k) {
    return ((r >> 4) << 12) | ((k >> 5) << 9) | (((k >> 3) & 3) << 7) |
           ((r & 15) << 3) | (k & 7);
}

__device__ inline float blockReduceSum(float v, float* lds) {
    for (int o = 32; o > 0; o >>= 1) v += __shfl_down(v, o);
    int lane = threadIdx.x & 63, wid = threadIdx.x >> 6;
    if (lane == 0) lds[wid] = v;
    __syncthreads();
    if (threadIdx.x == 0) {
        float r = lds[0];
        int nw = blockDim.x >> 6;
        for (int w = 1; w < nw; w++) r += lds[w];
        lds[0] = r;
    }
    __syncthreads();
    float r = lds[0];
    __syncthreads();
    return r;
}

// ---------------- 1) normalize, split bf16 hi/lo (swizzled), diag, zero acc -
__global__ void norm_kernel(const float* __restrict__ zis,
                            const float* __restrict__ zjs,
                            ushort* __restrict__ zhi, ushort* __restrict__ zlo,
                            ushort* __restrict__ whi, ushort* __restrict__ wlo,
                            float* __restrict__ diag, float* __restrict__ acc) {
    __shared__ float lds[8];
    int r = blockIdx.x;
    if (r == 0) { acc[threadIdx.x] = 0.f; acc[threadIdx.x + 256] = 0.f; }
    float zv = zis[r * DD + threadIdx.x];
    float wv = zjs[r * DD + threadIdx.x];
    float sz = blockReduceSum(zv * zv, lds);
    float sw = blockReduceSum(wv * wv, lds);
    float nz = zv * (1.0f / fmaxf(sqrtf(sz), 1e-12f));
    float nw = wv * (1.0f / fmaxf(sqrtf(sw), 1e-12f));
    float dt = blockReduceSum(nz * nw, lds);
    if (threadIdx.x == 0) diag[r] = dt;   // exact fp32 diagonal of sim
    __hip_bfloat16 hz = __float2bfloat16(nz);
    __hip_bfloat16 lz = __float2bfloat16(nz - __bfloat162float(hz));
    __hip_bfloat16 hw = __float2bfloat16(nw);
    __hip_bfloat16 lw = __float2bfloat16(nw - __bfloat162float(hw));
    int si = swz(r, threadIdx.x);
    zhi[si] = *(ushort*)&hz;
    zlo[si] = *(ushort*)&lz;
    whi[si] = *(ushort*)&hw;
    wlo[si] = *(ushort*)&lw;
}

// ---------------- 2) fused tile: barrier-free 3-MFMA + local-max partials ---
// No LDS staging: each wave loads its fragments directly from the swizzled
// global arrays (1KB coalesced per fragment, L2-resident). Zero __syncthreads
// in the K-loop -> no vmcnt(0) barrier drain; compiler pipelines freely.
__global__ void __launch_bounds__(256) fused_tile(const ushort* __restrict__ Ahi,
        const ushort* __restrict__ Alo, const ushort* __restrict__ Bhi,
        const ushort* __restrict__ Blo, const float* __restrict__ diag,
        const float* __restrict__ tausI, const float* __restrict__ tausT,
        const int* __restrict__ ids,
        float* __restrict__ pmR, float* __restrict__ pgR, float* __restrict__ pwR,
        float* __restrict__ pmC, float* __restrict__ pgC, float* __restrict__ pwC) {
    __shared__ float rDiag[128], rITau[128];
    __shared__ float cDiag[128], cITau[128];

    int lane = threadIdx.x & 63;
    int wv = threadIdx.x >> 6;
    int wm = wv >> 1, wn = wv & 1;
    int bm = blockIdx.y * 128, bn = blockIdx.x * 128;
    int ml = lane & 15, kq = lane >> 4;

    if (threadIdx.x < 128) {
        int r = bm + threadIdx.x;
        rDiag[threadIdx.x] = diag[r];
        rITau[threadIdx.x] = 1.0f / tausI[ids[r]];
    } else {
        int c = bn + threadIdx.x - 128;
        cDiag[threadIdx.x - 128] = diag[c];
        cITau[threadIdx.x - 128] = 1.0f / tausT[ids[c]];
    }

    // wave-uniform fragment bases (row_blk*4096), lane offset lane*8
    int aBlk = (bm >> 4) + wm * 4;   // + t
    int bBlk = (bn >> 4) + wn * 4;   // + u
    int lofs = lane * 8;

    f32x4 acc[4][4] = {};
#pragma unroll
    for (int s = 0; s < 8; s++) {
        int so = s * 512 + lofs;
        bf16x8 ah[4], al[4], bh[4], bl[4];
#pragma unroll
        for (int t = 0; t < 4; t++) {
            ah[t] = *(const bf16x8*)&Ahi[(aBlk + t) * 4096 + so];
            al[t] = *(const bf16x8*)&Alo[(aBlk + t) * 4096 + so];
            bh[t] = *(const bf16x8*)&Bhi[(bBlk + t) * 4096 + so];
            bl[t] = *(const bf16x8*)&Blo[(bBlk + t) * 4096 + so];
        }
#pragma unroll
        for (int t = 0; t < 4; t++)
#pragma unroll
            for (int u = 0; u < 4; u++) {
                acc[t][u] = __builtin_amdgcn_mfma_f32_16x16x32_bf16(ah[t], bh[u], acc[t][u], 0, 0, 0);
                acc[t][u] = __builtin_amdgcn_mfma_f32_16x16x32_bf16(ah[t], bl[u], acc[t][u], 0, 0, 0);
                acc[t][u] = __builtin_amdgcn_mfma_f32_16x16x32_bf16(al[t], bh[u], acc[t][u], 0, 0, 0);
            }
    }
    __syncthreads();  // params visible (only barrier in kernel body)

    // ---- epilogue ----
    float rd[4][4], rit[4][4];
    for (int t = 0; t < 4; t++)
        for (int reg = 0; reg < 4; reg++) {
            int rl = wm * 64 + t * 16 + kq * 4 + reg;
            rd[t][reg] = rDiag[rl];
            rit[t][reg] = rITau[rl];
        }
    // row-local max (this wave's 64 cols), idt units; includes diag (idt=0)
    float blocR[4][4];
    for (int t = 0; t < 4; t++)
        for (int reg = 0; reg < 4; reg++) {
            float m = fmaxf(fmaxf(acc[t][0][reg], acc[t][1][reg]),
                            fmaxf(acc[t][2][reg], acc[t][3][reg]));
            for (int mask = 1; mask <= 8; mask <<= 1)
                m = fmaxf(m, __shfl_xor(m, mask));
            blocR[t][reg] = (m - rd[t][reg]) * rit[t][reg];
        }
    // col-local max (this wave's 64 rows)
    float cd[4], cit[4], cbloc[4];
    for (int u = 0; u < 4; u++) {
        int cl = wn * 64 + u * 16 + ml;
        cd[u] = cDiag[cl];
        cit[u] = cITau[cl];
        float m = -INFINITY;
        for (int t = 0; t < 4; t++)
            for (int reg = 0; reg < 4; reg++)
                m = fmaxf(m, acc[t][u][reg]);
        for (int mask = 16; mask <= 32; mask <<= 1)
            m = fmaxf(m, __shfl_xor(m, mask));
        cbloc[u] = (m - cd[u]) * cit[u];
    }
    // exp pass vs local maxes
    float rg[4][4] = {}, rw[4][4] = {}, cg[4] = {}, cw[4] = {};
    for (int t = 0; t < 4; t++) {
        int gr0 = bm + wm * 64 + t * 16 + kq * 4;
        for (int u = 0; u < 4; u++) {
            int gc = bn + wn * 64 + u * 16 + ml;
            for (int reg = 0; reg < 4; reg++) {
                float v = acc[t][u][reg];
                bool off = (gr0 + reg) != gc;
                float dvI = v - rd[t][reg];
                float eI = off ? __expf(dvI * rit[t][reg] - blocR[t][reg]) : 0.f;
                rg[t][reg] += eI;
                rw[t][reg] += eI * dvI;
                float dvT = v - cd[u];
                float eT = off ? __expf(dvT * cit[u] - cbloc[u]) : 0.f;
                cg[u] += eT;
                cw[u] += eT * dvT;
            }
        }
    }
    // row reduce across ml lanes + vectorized store
    int stripeR = blockIdx.x * 2 + wn;
    for (int t = 0; t < 4; t++) {
        for (int reg = 0; reg < 4; reg++)
            for (int mask = 1; mask <= 8; mask <<= 1) {
                rg[t][reg] += __shfl_xor(rg[t][reg], mask);
                rw[t][reg] += __shfl_xor(rw[t][reg], mask);
            }
        if (ml == 0) {
            size_t o = (size_t)stripeR * BB + bm + wm * 64 + t * 16 + kq * 4;
            *(float4*)&pmR[o] = make_float4(blocR[t][0], blocR[t][1], blocR[t][2], blocR[t][3]);
            *(float4*)&pgR[o] = make_float4(rg[t][0], rg[t][1], rg[t][2], rg[t][3]);
            *(float4*)&pwR[o] = make_float4(rw[t][0], rw[t][1], rw[t][2], rw[t][3]);
        }
    }
    // col reduce across kq lanes + store
    int stripeC = blockIdx.y * 2 + wm;
    for (int u = 0; u < 4; u++) {
        for (int mask = 16; mask <= 32; mask <<= 1) {
            cg[u] += __shfl_xor(cg[u], mask);
            cw[u] += __shfl_xor(cw[u], mask);
        }
        if (kq == 0) {
            size_t o = (size_t)stripeC * BB + bn + wn * 64 + u * 16 + ml;
            pmC[o] = cbloc[u];
            pgC[o] = cg[u];
            pwC[o] = cw[u];
        }
    }
}

// acc layout: [0]=lossI [1]=lossT [2..101]=gradI [102..201]=cntI
//             [202..301]=gradT [302..401]=cntT
// ---------------- 3) finalize both sides (32 blocks: 16 row + 16 col) -------
__global__ void __launch_bounds__(256) fin_kernel(
        const float* __restrict__ pmR, const float* __restrict__ pgR,
        const float* __restrict__ pwR, const float* __restrict__ pmC,
        const float* __restrict__ pgC, const float* __restrict__ pwC,
        const float* __restrict__ sI, const float* __restrict__ bI,
        const float* __restrict__ tausI, const int* __restrict__ gInfI,
        const float* __restrict__ pI,
        const float* __restrict__ sT, const float* __restrict__ bT,
        const float* __restrict__ tausT, const int* __restrict__ gInfT,
        const float* __restrict__ pT,
        const int* __restrict__ ids, float* __restrict__ acc) {
    __shared__ float lds[8];
    __shared__ float binF[GG], binC[GG];
    if (threadIdx.x < GG) { binF[threadIdx.x] = 0.f; binC[threadIdx.x] = 0.f; }
    __syncthreads();
    int side = blockIdx.x >> 4;
    int i = (blockIdx.x & 15) * 256 + threadIdx.x;
    const float* pm = side ? pmC : pmR;
    const float* pg = side ? pgC : pgR;
    const float* pw = side ? pwC : pwR;
    const float* sS = side ? sT : sI;
    const float* bS = side ? bT : bI;
    const float* taus = side ? tausT : tausI;
    const int* ginfo = side ? gInfT : gInfI;
    const float* pP = side ? pT : pI;

    int id = ids[i];
    float oldb = bS[id];
    float m = -INFINITY;
    for (int s = 0; s < NS2; s++) m = fmaxf(m, pm[(size_t)s * BB + i]);
    float bfin = fmaxf(m, oldb);
    float g = 0.f, wsum = 0.f;
    for (int s = 0; s < NS2; s++) {
        float f = __expf(pm[(size_t)s * BB + i] - bfin);
        g += pg[(size_t)s * BB + i] * f;
        wsum += pw[(size_t)s * BB + i] * f;
    }
    float tau = taus[id];
    float snew = (1.f - GAMMA_C) * sS[id] * expf(oldb - bfin) + GAMMA_C * g;
    float sc = fmaxf(snew, EPS_C);
    int gid = ginfo[id];
    float gw = (float)GG * pP[gid];
    float loss = gw * wsum / sc;
    float F = tau * (logf(sc) + bfin + RHO_C);
    atomicAdd(&binF[gid], F);
    atomicAdd(&binC[gid], 1.0f);
    float lsum = blockReduceSum(loss, lds);
    if (threadIdx.x == 0) atomicAdd(&acc[side], lsum);
    __syncthreads();
    if (threadIdx.x < GG) {
        atomicAdd(&acc[2 + side * 200 + threadIdx.x], binF[threadIdx.x]);
        atomicAdd(&acc[102 + side * 200 + threadIdx.x], binC[threadIdx.x]);
    }
}

// ---------------- 4) finalize: p updates + total loss -----------------------
__global__ void final_kernel(const float* __restrict__ acc,
                             const float* __restrict__ zI, const float* __restrict__ zT,
                             const float* __restrict__ pI, const float* __restrict__ pT,
                             float* __restrict__ out) {
    __shared__ float sumsI[2], sumsT[2];
    int g = threadIdx.x;  // 128 threads
    float npI = 0.f, npT = 0.f;
    if (g < GG) {
        float cntI = fmaxf(acc[102 + g], 1.f);
        float gpI = acc[2 + g] / cntI;
        float zi = (1.f - GAMMA_C) * zI[g] + GAMMA_C * gpI;
        float ghpI = -logf(pI[g] + EPS_C) - 1.f;
        float ti = fminf(fmaxf(zi + ghpI, -5.f), 5.f);
        npI = pI[g] * expf(0.02f * ti);

        float cntT = fmaxf(acc[302 + g], 1.f);
        float gpT = acc[202 + g] / cntT;
        float zt = (1.f - GAMMA_C) * zT[g] + GAMMA_C * gpT;
        float ghpT = -logf(pT[g] + EPS_C) - 1.f;
        float tt = fminf(fmaxf(zt + ghpT, -5.f), 5.f);
        npT = pT[g] * expf(0.02f * tt);
    }
    float vI = npI, vT = npT;
    for (int o = 32; o > 0; o >>= 1) {
        vI += __shfl_down(vI, o);
        vT += __shfl_down(vT, o);
    }
    int wid = threadIdx.x >> 6, lane = threadIdx.x & 63;
    if (lane == 0) { sumsI[wid] = vI; sumsT[wid] = vT; }
    __syncthreads();
    float sumI = sumsI[0] + sumsI[1];
    float sumT = sumsT[0] + sumsT[1];
    if (g < GG) {
        out[1 + g] = npI / sumI;
        out[101 + g] = npT / sumT;
    }
    if (threadIdx.x == 0) {
        out[0] = ALPHA_C * (acc[0] / (float)BB) + (1.f - ALPHA_C) * (acc[1] / (float)BB);
    }
}

extern "C" void kernel_launch(void* const* d_in, const int* in_sizes, int n_in,
                              void* d_out, int out_size, void* d_ws, size_t ws_size,
                              hipStream_t stream) {
    const float* zis   = (const float*)d_in[0];
    const float* zjs   = (const float*)d_in[1];
    const float* s_I   = (const float*)d_in[2];
    const float* s_T   = (const float*)d_in[3];
    const float* b_I   = (const float*)d_in[4];
    const float* b_T   = (const float*)d_in[5];
    const float* z_I   = (const float*)d_in[6];
    const float* z_T   = (const float*)d_in[7];
    const float* p_I   = (const float*)d_in[8];
    const float* p_T   = (const float*)d_in[9];
    const float* tausI = (const float*)d_in[10];
    const float* tausT = (const float*)d_in[11];
    const int*   ids   = (const int*)d_in[12];
    const int*   gInfI = (const int*)d_in[13];
    const int*   gInfT = (const int*)d_in[14];
    float* out = (float*)d_out;

    char* ws = (char*)d_ws;
    ushort* zhi = (ushort*)ws;                         // BB*DD u16 each
    ushort* zlo = zhi + (size_t)BB * DD;
    ushort* whi = zlo + (size_t)BB * DD;
    ushort* wlo = whi + (size_t)BB * DD;
    float* acc  = (float*)(wlo + (size_t)BB * DD);     // 512
    float* diag = acc + 512;                           // BB
    float* pmR  = diag + BB;                           // NS2*BB each
    float* pgR  = pmR + (size_t)NS2 * BB;
    float* pwR  = pgR + (size_t)NS2 * BB;
    float* pmC  = pwR + (size_t)NS2 * BB;
    float* pgC  = pmC + (size_t)NS2 * BB;
    float* pwC  = pgC + (size_t)NS2 * BB;

    norm_kernel<<<BB, 256, 0, stream>>>(zis, zjs, zhi, zlo, whi, wlo, diag, acc);
    fused_tile<<<dim3(32, 32), 256, 0, stream>>>(zhi, zlo, whi, wlo, diag,
            tausI, tausT, ids, pmR, pgR, pwR, pmC, pgC, pwC);
    fin_kernel<<<32, 256, 0, stream>>>(pmR, pgR, pwR, pmC, pgC, pwC,
            s_I, b_I, tausI, gInfI, p_I, s_T, b_T, tausT, gInfT, p_T, ids, acc);
    final_kernel<<<1, 128, 0, stream>>>(acc, z_I, z_T, p_I, p_T, out);
}

// Round 8
// 321.404 us; speedup vs baseline: 1.0177x; 1.0177x over previous
//
#include <hip/hip_runtime.h>
#include <hip/hip_bf16.h>
#include <math.h>

#define BB 4096
#define DD 256
#define GG 100
#define GAMMA_C 0.8f
#define RHO_C 8.0f
#define ALPHA_C 0.5f
#define EPS_C 1e-14f
#define NS2 64   // 64 stripes (2 per 128-tile: one per 64-wide wave)

typedef __bf16 bf16x8 __attribute__((ext_vector_type(8)));
typedef float f32x4 __attribute__((ext_vector_type(4)));

// MFMA-fragment-swizzled layout: element (r,k) ->
//   row_blk=r>>4 (stride 4096), step=k>>5 (stride 512), kq2=(k>>3)&3 (128),
//   ml=r&15 (8), pos=k&7. Packs exactly; span = BB*DD.
__device__ inline int swz(int r, int k) {
    return ((r >> 4) << 12) | ((k >> 5) << 9) | (((k >> 3) & 3) << 7) |
           ((r & 15) << 3) | (k & 7);
}

__device__ inline float blockReduceSum(float v, float* lds) {
    for (int o = 32; o > 0; o >>= 1) v += __shfl_down(v, o);
    int lane = threadIdx.x & 63, wid = threadIdx.x >> 6;
    if (lane == 0) lds[wid] = v;
    __syncthreads();
    if (threadIdx.x == 0) {
        float r = lds[0];
        int nw = blockDim.x >> 6;
        for (int w = 1; w < nw; w++) r += lds[w];
        lds[0] = r;
    }
    __syncthreads();
    float r = lds[0];
    __syncthreads();
    return r;
}

// ---------------- 1) normalize, split bf16 hi/lo (swizzled), diag, zero acc -
__global__ void norm_kernel(const float* __restrict__ zis,
                            const float* __restrict__ zjs,
                            ushort* __restrict__ zhi, ushort* __restrict__ zlo,
                            ushort* __restrict__ whi, ushort* __restrict__ wlo,
                            float* __restrict__ diag, float* __restrict__ acc) {
    __shared__ float lds[8];
    int r = blockIdx.x;
    if (r == 0) { acc[threadIdx.x] = 0.f; acc[threadIdx.x + 256] = 0.f; }
    float zv = zis[r * DD + threadIdx.x];
    float wv = zjs[r * DD + threadIdx.x];
    float sz = blockReduceSum(zv * zv, lds);
    float sw = blockReduceSum(wv * wv, lds);
    float nz = zv * (1.0f / fmaxf(sqrtf(sz), 1e-12f));
    float nw = wv * (1.0f / fmaxf(sqrtf(sw), 1e-12f));
    float dt = blockReduceSum(nz * nw, lds);
    if (threadIdx.x == 0) diag[r] = dt;   // exact fp32 diagonal of sim
    __hip_bfloat16 hz = __float2bfloat16(nz);
    __hip_bfloat16 lz = __float2bfloat16(nz - __bfloat162float(hz));
    __hip_bfloat16 hw = __float2bfloat16(nw);
    __hip_bfloat16 lw = __float2bfloat16(nw - __bfloat162float(hw));
    int si = swz(r, threadIdx.x);
    zhi[si] = *(ushort*)&hz;
    zlo[si] = *(ushort*)&lz;
    whi[si] = *(ushort*)&hw;
    wlo[si] = *(ushort*)&lw;
}

// ---------------- 2) fused tile: barrier-free 3-MFMA + local-max partials ---
// No LDS staging; swizzled global fragment loads (1KB coalesced, L2-hit).
// __launch_bounds__(256,4): cap VGPR at 128 (R7 measured 132 -> 3 waves/SIMD;
// <=128 gives 4 waves/SIMD, +33% latency hiding on an all-pipes-idle kernel).
__global__ void __launch_bounds__(256, 4) fused_tile(const ushort* __restrict__ Ahi,
        const ushort* __restrict__ Alo, const ushort* __restrict__ Bhi,
        const ushort* __restrict__ Blo, const float* __restrict__ diag,
        const float* __restrict__ tausI, const float* __restrict__ tausT,
        const int* __restrict__ ids,
        float* __restrict__ pmR, float* __restrict__ pgR, float* __restrict__ pwR,
        float* __restrict__ pmC, float* __restrict__ pgC, float* __restrict__ pwC) {
    __shared__ float rDiag[128], rITau[128];
    __shared__ float cDiag[128], cITau[128];

    int lane = threadIdx.x & 63;
    int wv = threadIdx.x >> 6;
    int wm = wv >> 1, wn = wv & 1;
    int bm = blockIdx.y * 128, bn = blockIdx.x * 128;
    int ml = lane & 15, kq = lane >> 4;

    if (threadIdx.x < 128) {
        int r = bm + threadIdx.x;
        rDiag[threadIdx.x] = diag[r];
        rITau[threadIdx.x] = 1.0f / tausI[ids[r]];
    } else {
        int c = bn + threadIdx.x - 128;
        cDiag[threadIdx.x - 128] = diag[c];
        cITau[threadIdx.x - 128] = 1.0f / tausT[ids[c]];
    }

    // wave-uniform fragment bases (row_blk*4096), lane offset lane*8
    int aBlk = (bm >> 4) + wm * 4;   // + t
    int bBlk = (bn >> 4) + wn * 4;   // + u
    int lofs = lane * 8;

    f32x4 acc[4][4] = {};
#pragma unroll
    for (int s = 0; s < 8; s++) {
        int so = s * 512 + lofs;
        bf16x8 ah[4], al[4], bh[4], bl[4];
#pragma unroll
        for (int t = 0; t < 4; t++) {
            ah[t] = *(const bf16x8*)&Ahi[(aBlk + t) * 4096 + so];
            al[t] = *(const bf16x8*)&Alo[(aBlk + t) * 4096 + so];
            bh[t] = *(const bf16x8*)&Bhi[(bBlk + t) * 4096 + so];
            bl[t] = *(const bf16x8*)&Blo[(bBlk + t) * 4096 + so];
        }
#pragma unroll
        for (int t = 0; t < 4; t++)
#pragma unroll
            for (int u = 0; u < 4; u++) {
                acc[t][u] = __builtin_amdgcn_mfma_f32_16x16x32_bf16(ah[t], bh[u], acc[t][u], 0, 0, 0);
                acc[t][u] = __builtin_amdgcn_mfma_f32_16x16x32_bf16(ah[t], bl[u], acc[t][u], 0, 0, 0);
                acc[t][u] = __builtin_amdgcn_mfma_f32_16x16x32_bf16(al[t], bh[u], acc[t][u], 0, 0, 0);
            }
    }
    __syncthreads();  // params visible (only barrier in kernel body)

    // ---- epilogue ----
    float rd[4][4], rit[4][4];
    for (int t = 0; t < 4; t++)
        for (int reg = 0; reg < 4; reg++) {
            int rl = wm * 64 + t * 16 + kq * 4 + reg;
            rd[t][reg] = rDiag[rl];
            rit[t][reg] = rITau[rl];
        }
    // row-local max (this wave's 64 cols), idt units; includes diag (idt=0)
    float blocR[4][4];
    for (int t = 0; t < 4; t++)
        for (int reg = 0; reg < 4; reg++) {
            float m = fmaxf(fmaxf(acc[t][0][reg], acc[t][1][reg]),
                            fmaxf(acc[t][2][reg], acc[t][3][reg]));
            for (int mask = 1; mask <= 8; mask <<= 1)
                m = fmaxf(m, __shfl_xor(m, mask));
            blocR[t][reg] = (m - rd[t][reg]) * rit[t][reg];
        }
    // col-local max (this wave's 64 rows)
    float cd[4], cit[4], cbloc[4];
    for (int u = 0; u < 4; u++) {
        int cl = wn * 64 + u * 16 + ml;
        cd[u] = cDiag[cl];
        cit[u] = cITau[cl];
        float m = -INFINITY;
        for (int t = 0; t < 4; t++)
            for (int reg = 0; reg < 4; reg++)
                m = fmaxf(m, acc[t][u][reg]);
        for (int mask = 16; mask <= 32; mask <<= 1)
            m = fmaxf(m, __shfl_xor(m, mask));
        cbloc[u] = (m - cd[u]) * cit[u];
    }
    // exp pass vs local maxes
    float rg[4][4] = {}, rw[4][4] = {}, cg[4] = {}, cw[4] = {};
    for (int t = 0; t < 4; t++) {
        int gr0 = bm + wm * 64 + t * 16 + kq * 4;
        for (int u = 0; u < 4; u++) {
            int gc = bn + wn * 64 + u * 16 + ml;
            for (int reg = 0; reg < 4; reg++) {
                float v = acc[t][u][reg];
                bool off = (gr0 + reg) != gc;
                float dvI = v - rd[t][reg];
                float eI = off ? __expf(dvI * rit[t][reg] - blocR[t][reg]) : 0.f;
                rg[t][reg] += eI;
                rw[t][reg] += eI * dvI;
                float dvT = v - cd[u];
                float eT = off ? __expf(dvT * cit[u] - cbloc[u]) : 0.f;
                cg[u] += eT;
                cw[u] += eT * dvT;
            }
        }
    }
    // row reduce across ml lanes + vectorized store
    int stripeR = blockIdx.x * 2 + wn;
    for (int t = 0; t < 4; t++) {
        for (int reg = 0; reg < 4; reg++)
            for (int mask = 1; mask <= 8; mask <<= 1) {
                rg[t][reg] += __shfl_xor(rg[t][reg], mask);
                rw[t][reg] += __shfl_xor(rw[t][reg], mask);
            }
        if (ml == 0) {
            size_t o = (size_t)stripeR * BB + bm + wm * 64 + t * 16 + kq * 4;
            *(float4*)&pmR[o] = make_float4(blocR[t][0], blocR[t][1], blocR[t][2], blocR[t][3]);
            *(float4*)&pgR[o] = make_float4(rg[t][0], rg[t][1], rg[t][2], rg[t][3]);
            *(float4*)&pwR[o] = make_float4(rw[t][0], rw[t][1], rw[t][2], rw[t][3]);
        }
    }
    // col reduce across kq lanes + store
    int stripeC = blockIdx.y * 2 + wm;
    for (int u = 0; u < 4; u++) {
        for (int mask = 16; mask <= 32; mask <<= 1) {
            cg[u] += __shfl_xor(cg[u], mask);
            cw[u] += __shfl_xor(cw[u], mask);
        }
        if (kq == 0) {
            size_t o = (size_t)stripeC * BB + bn + wn * 64 + u * 16 + ml;
            pmC[o] = cbloc[u];
            pgC[o] = cg[u];
            pwC[o] = cw[u];
        }
    }
}

// acc layout: [0]=lossI [1]=lossT [2..101]=gradI [102..201]=cntI
//             [202..301]=gradT [302..401]=cntT  [408]=completion counter(int)
// ---------------- 3) finalize both sides + last-block p-update --------------
__global__ void __launch_bounds__(256) fin_kernel(
        const float* __restrict__ pmR, const float* __restrict__ pgR,
        const float* __restrict__ pwR, const float* __restrict__ pmC,
        const float* __restrict__ pgC, const float* __restrict__ pwC,
        const float* __restrict__ sI, const float* __restrict__ bI,
        const float* __restrict__ tausI, const int* __restrict__ gInfI,
        const float* __restrict__ pI,
        const float* __restrict__ sT, const float* __restrict__ bT,
        const float* __restrict__ tausT, const int* __restrict__ gInfT,
        const float* __restrict__ pT,
        const int* __restrict__ ids, float* __restrict__ acc,
        const float* __restrict__ zI, const float* __restrict__ zT,
        float* __restrict__ out) {
    __shared__ float lds[8];
    __shared__ float binF[GG], binC[GG];
    __shared__ int lastFlag;
    if (threadIdx.x < GG) { binF[threadIdx.x] = 0.f; binC[threadIdx.x] = 0.f; }
    __syncthreads();
    int side = blockIdx.x >> 4;
    int i = (blockIdx.x & 15) * 256 + threadIdx.x;
    const float* pm = side ? pmC : pmR;
    const float* pg = side ? pgC : pgR;
    const float* pw = side ? pwC : pwR;
    const float* sS = side ? sT : sI;
    const float* bS = side ? bT : bI;
    const float* taus = side ? tausT : tausI;
    const int* ginfo = side ? gInfT : gInfI;
    const float* pP = side ? pT : pI;

    int id = ids[i];
    float oldb = bS[id];
    float m = -INFINITY;
    for (int s = 0; s < NS2; s++) m = fmaxf(m, pm[(size_t)s * BB + i]);
    float bfin = fmaxf(m, oldb);
    float g = 0.f, wsum = 0.f;
    for (int s = 0; s < NS2; s++) {
        float f = __expf(pm[(size_t)s * BB + i] - bfin);
        g += pg[(size_t)s * BB + i] * f;
        wsum += pw[(size_t)s * BB + i] * f;
    }
    float tau = taus[id];
    float snew = (1.f - GAMMA_C) * sS[id] * expf(oldb - bfin) + GAMMA_C * g;
    float sc = fmaxf(snew, EPS_C);
    int gid = ginfo[id];
    float gw = (float)GG * pP[gid];
    float loss = gw * wsum / sc;
    float F = tau * (logf(sc) + bfin + RHO_C);
    atomicAdd(&binF[gid], F);
    atomicAdd(&binC[gid], 1.0f);
    float lsum = blockReduceSum(loss, lds);
    if (threadIdx.x == 0) atomicAdd(&acc[side], lsum);
    __syncthreads();
    if (threadIdx.x < GG) {
        atomicAdd(&acc[2 + side * 200 + threadIdx.x], binF[threadIdx.x]);
        atomicAdd(&acc[102 + side * 200 + threadIdx.x], binC[threadIdx.x]);
    }

    // ---- completion counter: last of 32 blocks runs the p-update phase ----
    __threadfence();  // make this block's atomics visible device-wide
    if (threadIdx.x == 0) {
        int old = atomicAdd((int*)&acc[408], 1);
        lastFlag = (old == 31);
    }
    __syncthreads();
    if (!lastFlag) return;

    // final phase (all 256 threads participate; only tid<GG contribute)
    int gg = threadIdx.x;
    float npI = 0.f, npT = 0.f;
    if (gg < GG) {
        float cI = __hip_atomic_load(&acc[102 + gg], __ATOMIC_RELAXED, __HIP_MEMORY_SCOPE_AGENT);
        float fI = __hip_atomic_load(&acc[2 + gg], __ATOMIC_RELAXED, __HIP_MEMORY_SCOPE_AGENT);
        float gpI = fI / fmaxf(cI, 1.f);
        float zi = (1.f - GAMMA_C) * zI[gg] + GAMMA_C * gpI;
        float ghpI = -logf(pI[gg] + EPS_C) - 1.f;
        float ti = fminf(fmaxf(zi + ghpI, -5.f), 5.f);
        npI = pI[gg] * expf(0.02f * ti);

        float cT = __hip_atomic_load(&acc[302 + gg], __ATOMIC_RELAXED, __HIP_MEMORY_SCOPE_AGENT);
        float fT = __hip_atomic_load(&acc[202 + gg], __ATOMIC_RELAXED, __HIP_MEMORY_SCOPE_AGENT);
        float gpT = fT / fmaxf(cT, 1.f);
        float zt = (1.f - GAMMA_C) * zT[gg] + GAMMA_C * gpT;
        float ghpT = -logf(pT[gg] + EPS_C) - 1.f;
        float tt = fminf(fmaxf(zt + ghpT, -5.f), 5.f);
        npT = pT[gg] * expf(0.02f * tt);
    }
    float sumI = blockReduceSum(npI, lds);
    float sumT = blockReduceSum(npT, lds);
    if (gg < GG) {
        out[1 + gg] = npI / sumI;
        out[101 + gg] = npT / sumT;
    }
    if (gg == 0) {
        float lI = __hip_atomic_load(&acc[0], __ATOMIC_RELAXED, __HIP_MEMORY_SCOPE_AGENT);
        float lT = __hip_atomic_load(&acc[1], __ATOMIC_RELAXED, __HIP_MEMORY_SCOPE_AGENT);
        out[0] = ALPHA_C * (lI / (float)BB) + (1.f - ALPHA_C) * (lT / (float)BB);
    }
}

extern "C" void kernel_launch(void* const* d_in, const int* in_sizes, int n_in,
                              void* d_out, int out_size, void* d_ws, size_t ws_size,
                              hipStream_t stream) {
    const float* zis   = (const float*)d_in[0];
    const float* zjs   = (const float*)d_in[1];
    const float* s_I   = (const float*)d_in[2];
    const float* s_T   = (const float*)d_in[3];
    const float* b_I   = (const float*)d_in[4];
    const float* b_T   = (const float*)d_in[5];
    const float* z_I   = (const float*)d_in[6];
    const float* z_T   = (const float*)d_in[7];
    const float* p_I   = (const float*)d_in[8];
    const float* p_T   = (const float*)d_in[9];
    const float* tausI = (const float*)d_in[10];
    const float* tausT = (const float*)d_in[11];
    const int*   ids   = (const int*)d_in[12];
    const int*   gInfI = (const int*)d_in[13];
    const int*   gInfT = (const int*)d_in[14];
    float* out = (float*)d_out;

    char* ws = (char*)d_ws;
    ushort* zhi = (ushort*)ws;                         // BB*DD u16 each
    ushort* zlo = zhi + (size_t)BB * DD;
    ushort* whi = zlo + (size_t)BB * DD;
    ushort* wlo = whi + (size_t)BB * DD;
    float* acc  = (float*)(wlo + (size_t)BB * DD);     // 512
    float* diag = acc + 512;                           // BB
    float* pmR  = diag + BB;                           // NS2*BB each
    float* pgR  = pmR + (size_t)NS2 * BB;
    float* pwR  = pgR + (size_t)NS2 * BB;
    float* pmC  = pwR + (size_t)NS2 * BB;
    float* pgC  = pmC + (size_t)NS2 * BB;
    float* pwC  = pgC + (size_t)NS2 * BB;

    norm_kernel<<<BB, 256, 0, stream>>>(zis, zjs, zhi, zlo, whi, wlo, diag, acc);
    fused_tile<<<dim3(32, 32), 256, 0, stream>>>(zhi, zlo, whi, wlo, diag,
            tausI, tausT, ids, pmR, pgR, pwR, pmC, pgC, pwC);
    fin_kernel<<<32, 256, 0, stream>>>(pmR, pgR, pwR, pmC, pgC, pwC,
            s_I, b_I, tausI, gInfI, p_I, s_T, b_T, tausT, gInfT, p_T, ids, acc,
            z_I, z_T, out);
}

// Round 9
// 309.756 us; speedup vs baseline: 1.0559x; 1.0376x over previous
//
#include <hip/hip_runtime.h>
#include <hip/hip_bf16.h>
#include <math.h>

#define BB 4096
#define DD 256
#define GG 100
#define GAMMA_C 0.8f
#define RHO_C 8.0f
#define ALPHA_C 0.5f
#define EPS_C 1e-14f
#define NS2 64   // 64 stripes (2 per 128-tile: one per 64-wide wave)

typedef __bf16 bf16x8 __attribute__((ext_vector_type(8)));
typedef float f32x16 __attribute__((ext_vector_type(16)));

// 32-row fragment-swizzled layout for mfma_32x32x16: element (r,k) ->
//   row_blk=r>>5 (stride 8192 = 32 rows x 256 k), step=k>>4 (stride 512),
//   lane=((k>>3)&1)*32 + (r&31) (stride 8), pos=k&7. Packs exactly.
// Wave fragment load = base + lane*8 -> one contiguous 1KB dwordx4/lane load.
__device__ inline int swz32(int r, int k) {
    return ((r >> 5) << 13) | ((k >> 4) << 9) |
           (((((k >> 3) & 1) << 5) | (r & 31)) << 3) | (k & 7);
}

__device__ inline float blockReduceSum(float v, float* lds) {
    for (int o = 32; o > 0; o >>= 1) v += __shfl_down(v, o);
    int lane = threadIdx.x & 63, wid = threadIdx.x >> 6;
    if (lane == 0) lds[wid] = v;
    __syncthreads();
    if (threadIdx.x == 0) {
        float r = lds[0];
        int nw = blockDim.x >> 6;
        for (int w = 1; w < nw; w++) r += lds[w];
        lds[0] = r;
    }
    __syncthreads();
    float r = lds[0];
    __syncthreads();
    return r;
}

// ---------------- 1) normalize, split bf16 hi/lo (swizzled), diag, zero acc -
__global__ void norm_kernel(const float* __restrict__ zis,
                            const float* __restrict__ zjs,
                            ushort* __restrict__ zhi, ushort* __restrict__ zlo,
                            ushort* __restrict__ whi, ushort* __restrict__ wlo,
                            float* __restrict__ diag, float* __restrict__ acc) {
    __shared__ float lds[8];
    int r = blockIdx.x;
    if (r == 0) { acc[threadIdx.x] = 0.f; acc[threadIdx.x + 256] = 0.f; }
    float zv = zis[r * DD + threadIdx.x];
    float wv = zjs[r * DD + threadIdx.x];
    float sz = blockReduceSum(zv * zv, lds);
    float sw = blockReduceSum(wv * wv, lds);
    float nz = zv * (1.0f / fmaxf(sqrtf(sz), 1e-12f));
    float nw = wv * (1.0f / fmaxf(sqrtf(sw), 1e-12f));
    float dt = blockReduceSum(nz * nw, lds);
    if (threadIdx.x == 0) diag[r] = dt;   // exact fp32 diagonal of sim
    __hip_bfloat16 hz = __float2bfloat16(nz);
    __hip_bfloat16 lz = __float2bfloat16(nz - __bfloat162float(hz));
    __hip_bfloat16 hw = __float2bfloat16(nw);
    __hip_bfloat16 lw = __float2bfloat16(nw - __bfloat162float(hw));
    int si = swz32(r, threadIdx.x);
    zhi[si] = *(ushort*)&hz;
    zlo[si] = *(ushort*)&lz;
    whi[si] = *(ushort*)&hw;
    wlo[si] = *(ushort*)&lw;
}

// ---------------- 2) fused tile: 32x32x16 MFMA, barrier-free ----------------
// Per K-step only 8 live fragments (32 VGPRs) vs 16 (64) with 16x16 MFMA,
// so acc(64 AGPR)+frags+addr fits the 128-reg/4-blocks-per-CU budget without
// the scratch spills R8 measured (WRITE_SIZE 78MB). C/D layout [m74/m101]:
// col=lane&31, row=(reg&3)+8*(reg>>2)+4*(lane>>5).
__global__ void __launch_bounds__(256, 4) fused_tile(const ushort* __restrict__ Ahi,
        const ushort* __restrict__ Alo, const ushort* __restrict__ Bhi,
        const ushort* __restrict__ Blo, const float* __restrict__ diag,
        const float* __restrict__ tausI, const float* __restrict__ tausT,
        const int* __restrict__ ids,
        float* __restrict__ pmR, float* __restrict__ pgR, float* __restrict__ pwR,
        float* __restrict__ pmC, float* __restrict__ pgC, float* __restrict__ pwC) {
    __shared__ float rDiag[128], rITau[128];
    __shared__ float cDiag[128], cITau[128];

    int lane = threadIdx.x & 63;
    int wv = threadIdx.x >> 6;
    int wm = wv >> 1, wn = wv & 1;
    int bm = blockIdx.y * 128, bn = blockIdx.x * 128;
    int h = lane >> 5, cl = lane & 31;

    if (threadIdx.x < 128) {
        int r = bm + threadIdx.x;
        rDiag[threadIdx.x] = diag[r];
        rITau[threadIdx.x] = 1.0f / tausI[ids[r]];
    } else {
        int c = bn + threadIdx.x - 128;
        cDiag[threadIdx.x - 128] = diag[c];
        cITau[threadIdx.x - 128] = 1.0f / tausT[ids[c]];
    }

    // fragment bases: 32-row blocks
    int aBlk = (bm >> 5) + wm * 2;   // + t
    int bBlk = (bn >> 5) + wn * 2;   // + u
    int lofs = lane * 8;

    f32x16 acc[2][2] = {};
#pragma unroll
    for (int s = 0; s < 16; s++) {
        int so = s * 512 + lofs;
        bf16x8 ah[2], al[2], bh[2], bl[2];
#pragma unroll
        for (int t = 0; t < 2; t++) {
            ah[t] = *(const bf16x8*)&Ahi[(aBlk + t) * 8192 + so];
            al[t] = *(const bf16x8*)&Alo[(aBlk + t) * 8192 + so];
            bh[t] = *(const bf16x8*)&Bhi[(bBlk + t) * 8192 + so];
            bl[t] = *(const bf16x8*)&Blo[(bBlk + t) * 8192 + so];
        }
#pragma unroll
        for (int t = 0; t < 2; t++)
#pragma unroll
            for (int u = 0; u < 2; u++) {
                acc[t][u] = __builtin_amdgcn_mfma_f32_32x32x16_bf16(ah[t], bh[u], acc[t][u], 0, 0, 0);
                acc[t][u] = __builtin_amdgcn_mfma_f32_32x32x16_bf16(ah[t], bl[u], acc[t][u], 0, 0, 0);
                acc[t][u] = __builtin_amdgcn_mfma_f32_32x32x16_bf16(al[t], bh[u], acc[t][u], 0, 0, 0);
            }
    }
    __syncthreads();  // params visible (only barrier in kernel body)

    // ---- epilogue ----
    // col params (per lane: cols wn*64 + u*32 + cl)
    float cd[2], cit[2];
    for (int u = 0; u < 2; u++) {
        int clloc = wn * 64 + u * 32 + cl;
        cd[u] = cDiag[clloc];
        cit[u] = cITau[clloc];
    }

    // ---- col side first (few temporaries) ----
    float cbloc[2], cg[2] = {}, cw[2] = {};
    for (int u = 0; u < 2; u++) {
        float m = -INFINITY;
        for (int t = 0; t < 2; t++)
            for (int reg = 0; reg < 16; reg++)
                m = fmaxf(m, acc[t][u][reg]);
        m = fmaxf(m, __shfl_xor(m, 32));
        cbloc[u] = (m - cd[u]) * cit[u];
    }
    for (int t = 0; t < 2; t++)
        for (int u = 0; u < 2; u++) {
            int gc = bn + wn * 64 + u * 32 + cl;
            for (int reg = 0; reg < 16; reg++) {
                int gr = bm + wm * 64 + t * 32 + (reg & 3) + 4 * h + 8 * (reg >> 2);
                float v = acc[t][u][reg];
                bool off = gr != gc;
                float dvT = v - cd[u];
                float eT = off ? __expf(dvT * cit[u] - cbloc[u]) : 0.f;
                cg[u] += eT;
                cw[u] += eT * dvT;
            }
        }
    int stripeC = blockIdx.y * 2 + wm;
    for (int u = 0; u < 2; u++) {
        cg[u] += __shfl_xor(cg[u], 32);
        cw[u] += __shfl_xor(cw[u], 32);
        if (h == 0) {
            size_t o = (size_t)stripeC * BB + bn + wn * 64 + u * 32 + cl;
            pmC[o] = cbloc[u];
            pgC[o] = cg[u];
            pwC[o] = cw[u];
        }
    }

    // ---- row side: per (t, quad q) to bound live temporaries ----
    // rows of quad q: 8q + 4h + {0..3}  (regs 4q+j)
    int stripeR = blockIdx.x * 2 + wn;
    for (int t = 0; t < 2; t++)
        for (int q = 0; q < 4; q++) {
            float rd4[4], rit4[4], bloc[4], rg[4] = {}, rw[4] = {};
            for (int j = 0; j < 4; j++) {
                int rl = wm * 64 + t * 32 + 8 * q + 4 * h + j;
                rd4[j] = rDiag[rl];
                rit4[j] = rITau[rl];
            }
            for (int j = 0; j < 4; j++) {
                float m = fmaxf(acc[t][0][4 * q + j], acc[t][1][4 * q + j]);
                for (int mask = 1; mask <= 16; mask <<= 1)
                    m = fmaxf(m, __shfl_xor(m, mask));
                bloc[j] = (m - rd4[j]) * rit4[j];
            }
            for (int u = 0; u < 2; u++) {
                int gc = bn + wn * 64 + u * 32 + cl;
                for (int j = 0; j < 4; j++) {
                    int gr = bm + wm * 64 + t * 32 + 8 * q + 4 * h + j;
                    float v = acc[t][u][4 * q + j];
                    bool off = gr != gc;
                    float dvI = v - rd4[j];
                    float eI = off ? __expf(dvI * rit4[j] - bloc[j]) : 0.f;
                    rg[j] += eI;
                    rw[j] += eI * dvI;
                }
            }
            for (int j = 0; j < 4; j++)
                for (int mask = 1; mask <= 16; mask <<= 1) {
                    rg[j] += __shfl_xor(rg[j], mask);
                    rw[j] += __shfl_xor(rw[j], mask);
                }
            if (cl == 0) {   // one lane per h-half writes 4 contiguous rows
                size_t o = (size_t)stripeR * BB + bm + wm * 64 + t * 32 + 8 * q + 4 * h;
                *(float4*)&pmR[o] = make_float4(bloc[0], bloc[1], bloc[2], bloc[3]);
                *(float4*)&pgR[o] = make_float4(rg[0], rg[1], rg[2], rg[3]);
                *(float4*)&pwR[o] = make_float4(rw[0], rw[1], rw[2], rw[3]);
            }
        }
}

// acc layout: [0]=lossI [1]=lossT [2..101]=gradI [102..201]=cntI
//             [202..301]=gradT [302..401]=cntT  [408]=completion counter(int)
// ---------------- 3) finalize both sides + last-block p-update --------------
__global__ void __launch_bounds__(256) fin_kernel(
        const float* __restrict__ pmR, const float* __restrict__ pgR,
        const float* __restrict__ pwR, const float* __restrict__ pmC,
        const float* __restrict__ pgC, const float* __restrict__ pwC,
        const float* __restrict__ sI, const float* __restrict__ bI,
        const float* __restrict__ tausI, const int* __restrict__ gInfI,
        const float* __restrict__ pI,
        const float* __restrict__ sT, const float* __restrict__ bT,
        const float* __restrict__ tausT, const int* __restrict__ gInfT,
        const float* __restrict__ pT,
        const int* __restrict__ ids, float* __restrict__ acc,
        const float* __restrict__ zI, const float* __restrict__ zT,
        float* __restrict__ out) {
    __shared__ float lds[8];
    __shared__ float binF[GG], binC[GG];
    __shared__ int lastFlag;
    if (threadIdx.x < GG) { binF[threadIdx.x] = 0.f; binC[threadIdx.x] = 0.f; }
    __syncthreads();
    int side = blockIdx.x >> 4;
    int i = (blockIdx.x & 15) * 256 + threadIdx.x;
    const float* pm = side ? pmC : pmR;
    const float* pg = side ? pgC : pgR;
    const float* pw = side ? pwC : pwR;
    const float* sS = side ? sT : sI;
    const float* bS = side ? bT : bI;
    const float* taus = side ? tausT : tausI;
    const int* ginfo = side ? gInfT : gInfI;
    const float* pP = side ? pT : pI;

    int id = ids[i];
    float oldb = bS[id];
    float m = -INFINITY;
    for (int s = 0; s < NS2; s++) m = fmaxf(m, pm[(size_t)s * BB + i]);
    float bfin = fmaxf(m, oldb);
    float g = 0.f, wsum = 0.f;
    for (int s = 0; s < NS2; s++) {
        float f = __expf(pm[(size_t)s * BB + i] - bfin);
        g += pg[(size_t)s * BB + i] * f;
        wsum += pw[(size_t)s * BB + i] * f;
    }
    float tau = taus[id];
    float snew = (1.f - GAMMA_C) * sS[id] * expf(oldb - bfin) + GAMMA_C * g;
    float sc = fmaxf(snew, EPS_C);
    int gid = ginfo[id];
    float gw = (float)GG * pP[gid];
    float loss = gw * wsum / sc;
    float F = tau * (logf(sc) + bfin + RHO_C);
    atomicAdd(&binF[gid], F);
    atomicAdd(&binC[gid], 1.0f);
    float lsum = blockReduceSum(loss, lds);
    if (threadIdx.x == 0) atomicAdd(&acc[side], lsum);
    __syncthreads();
    if (threadIdx.x < GG) {
        atomicAdd(&acc[2 + side * 200 + threadIdx.x], binF[threadIdx.x]);
        atomicAdd(&acc[102 + side * 200 + threadIdx.x], binC[threadIdx.x]);
    }

    // ---- completion counter: last of 32 blocks runs the p-update phase ----
    __threadfence();  // make this block's atomics visible device-wide
    if (threadIdx.x == 0) {
        int old = atomicAdd((int*)&acc[408], 1);
        lastFlag = (old == 31);
    }
    __syncthreads();
    if (!lastFlag) return;

    // final phase (all 256 threads participate; only tid<GG contribute)
    int gg = threadIdx.x;
    float npI = 0.f, npT = 0.f;
    if (gg < GG) {
        float cI = __hip_atomic_load(&acc[102 + gg], __ATOMIC_RELAXED, __HIP_MEMORY_SCOPE_AGENT);
        float fI = __hip_atomic_load(&acc[2 + gg], __ATOMIC_RELAXED, __HIP_MEMORY_SCOPE_AGENT);
        float gpI = fI / fmaxf(cI, 1.f);
        float zi = (1.f - GAMMA_C) * zI[gg] + GAMMA_C * gpI;
        float ghpI = -logf(pI[gg] + EPS_C) - 1.f;
        float ti = fminf(fmaxf(zi + ghpI, -5.f), 5.f);
        npI = pI[gg] * expf(0.02f * ti);

        float cT = __hip_atomic_load(&acc[302 + gg], __ATOMIC_RELAXED, __HIP_MEMORY_SCOPE_AGENT);
        float fT = __hip_atomic_load(&acc[202 + gg], __ATOMIC_RELAXED, __HIP_MEMORY_SCOPE_AGENT);
        float gpT = fT / fmaxf(cT, 1.f);
        float zt = (1.f - GAMMA_C) * zT[gg] + GAMMA_C * gpT;
        float ghpT = -logf(pT[gg] + EPS_C) - 1.f;
        float tt = fminf(fmaxf(zt + ghpT, -5.f), 5.f);
        npT = pT[gg] * expf(0.02f * tt);
    }
    float sumI = blockReduceSum(npI, lds);
    float sumT = blockReduceSum(npT, lds);
    if (gg < GG) {
        out[1 + gg] = npI / sumI;
        out[101 + gg] = npT / sumT;
    }
    if (gg == 0) {
        float lI = __hip_atomic_load(&acc[0], __ATOMIC_RELAXED, __HIP_MEMORY_SCOPE_AGENT);
        float lT = __hip_atomic_load(&acc[1], __ATOMIC_RELAXED, __HIP_MEMORY_SCOPE_AGENT);
        out[0] = ALPHA_C * (lI / (float)BB) + (1.f - ALPHA_C) * (lT / (float)BB);
    }
}

extern "C" void kernel_launch(void* const* d_in, const int* in_sizes, int n_in,
                              void* d_out, int out_size, void* d_ws, size_t ws_size,
                              hipStream_t stream) {
    const float* zis   = (const float*)d_in[0];
    const float* zjs   = (const float*)d_in[1];
    const float* s_I   = (const float*)d_in[2];
    const float* s_T   = (const float*)d_in[3];
    const float* b_I   = (const float*)d_in[4];
    const float* b_T   = (const float*)d_in[5];
    const float* z_I   = (const float*)d_in[6];
    const float* z_T   = (const float*)d_in[7];
    const float* p_I   = (const float*)d_in[8];
    const float* p_T   = (const float*)d_in[9];
    const float* tausI = (const float*)d_in[10];
    const float* tausT = (const float*)d_in[11];
    const int*   ids   = (const int*)d_in[12];
    const int*   gInfI = (const int*)d_in[13];
    const int*   gInfT = (const int*)d_in[14];
    float* out = (float*)d_out;

    char* ws = (char*)d_ws;
    ushort* zhi = (ushort*)ws;                         // BB*DD u16 each
    ushort* zlo = zhi + (size_t)BB * DD;
    ushort* whi = zlo + (size_t)BB * DD;
    ushort* wlo = whi + (size_t)BB * DD;
    float* acc  = (float*)(wlo + (size_t)BB * DD);     // 512
    float* diag = acc + 512;                           // BB
    float* pmR  = diag + BB;                           // NS2*BB each
    float* pgR  = pmR + (size_t)NS2 * BB;
    float* pwR  = pgR + (size_t)NS2 * BB;
    float* pmC  = pwR + (size_t)NS2 * BB;
    float* pgC  = pmC + (size_t)NS2 * BB;
    float* pwC  = pgC + (size_t)NS2 * BB;

    norm_kernel<<<BB, 256, 0, stream>>>(zis, zjs, zhi, zlo, whi, wlo, diag, acc);
    fused_tile<<<dim3(32, 32), 256, 0, stream>>>(zhi, zlo, whi, wlo, diag,
            tausI, tausT, ids, pmR, pgR, pwR, pmC, pgC, pwC);
    fin_kernel<<<32, 256, 0, stream>>>(pmR, pgR, pwR, pmC, pgC, pwC,
            s_I, b_I, tausI, gInfI, p_I, s_T, b_T, tausT, gInfT, p_T, ids, acc,
            z_I, z_T, out);
}